// Round 10
// baseline (3366.261 us; speedup 1.0000x reference)
//
#include <hip/hip_runtime.h>

#define NB 4
#define NPTS 8192
#define NPOINT 2048
#define NSAMPLE 32
#define CF 64      // feature channels
#define CIN 67     // 3 + 64
#define G 8        // centers per MLP block

typedef float f32x2 __attribute__((ext_vector_type(2)));
typedef unsigned long long u64;

__device__ __forceinline__ f32x2 pk_add(f32x2 a, f32x2 b) {
  f32x2 d;
  asm("v_pk_add_f32 %0, %1, %2" : "=v"(d) : "v"(a), "v"(b));
  return d;
}
__device__ __forceinline__ f32x2 pk_mul(f32x2 a, f32x2 b) {
  f32x2 d;
  asm("v_pk_mul_f32 %0, %1, %2" : "=v"(d) : "v"(a), "v"(b));
  return d;
}

template <int CTRL, int RM>
__device__ __forceinline__ int dppi(int v) {
  return __builtin_amdgcn_update_dpp(0, v, CTRL, RM, 0xf, true);
}
// key = (f32 dist bits << 32) | ~origidx, always < 0x7FF0.. as u64 ->
// positive double whose IEEE order == u64 order. One v_max_f64 per merge.
__device__ __forceinline__ double kmax(double a, double b) { return fmax(a, b); }
__device__ __forceinline__ double mkkey(unsigned hi, unsigned lo) {
  return __longlong_as_double(((long long)hi << 32) | lo);
}
template <int CTRL, int RM>
__device__ __forceinline__ double kstep_d(double k) {
  long long bb = __double_as_longlong(k);
  unsigned lo = (unsigned)bb, hi = (unsigned)(bb >> 32);
  unsigned olo = (unsigned)dppi<CTRL, RM>((int)lo);
  unsigned ohi = (unsigned)dppi<CTRL, RM>((int)hi);
  double o = __longlong_as_double(((long long)ohi << 32) | olo);
  return fmax(k, o);
}
__device__ __forceinline__ double wave_max_key_d(double key) {
  key = kstep_d<0x111, 0xf>(key);  // row_shr:1
  key = kstep_d<0x112, 0xf>(key);  // row_shr:2
  key = kstep_d<0x114, 0xf>(key);  // row_shr:4
  key = kstep_d<0x118, 0xf>(key);  // row_shr:8
  key = kstep_d<0x142, 0xa>(key);  // row_bcast:15
  key = kstep_d<0x143, 0xc>(key);  // row_bcast:31
  return key;
}
// wave-64 inclusive add-scan (valid all lanes; lane63 = total)
__device__ __forceinline__ unsigned wave_scan_incl(unsigned v) {
  v += (unsigned)__builtin_amdgcn_update_dpp(0, (int)v, 0x111, 0xf, 0xf, true);
  v += (unsigned)__builtin_amdgcn_update_dpp(0, (int)v, 0x112, 0xf, 0xf, true);
  v += (unsigned)__builtin_amdgcn_update_dpp(0, (int)v, 0x114, 0xf, 0xf, true);
  v += (unsigned)__builtin_amdgcn_update_dpp(0, (int)v, 0x118, 0xf, 0xf, true);
  v += (unsigned)__builtin_amdgcn_update_dpp(0, (int)v, 0x142, 0xa, 0xf, true);
  v += (unsigned)__builtin_amdgcn_update_dpp(0, (int)v, 0x143, 0xc, 0xf, true);
  return v;
}

__device__ __forceinline__ int cell16(float x) {
  int c = (int)(x * 16.0f);
  return c > 15 ? 15 : (c < 0 ? 0 : c);
}
__device__ __forceinline__ unsigned morton12(int ix, int iy, int iz) {
  unsigned m = 0;
#pragma unroll
  for (int k = 0; k < 4; ++k) {
    m |= ((unsigned)((ix >> k) & 1) << (3 * k + 2)) |
         ((unsigned)((iy >> k) & 1) << (3 * k + 1)) |
         ((unsigned)((iz >> k) & 1) << (3 * k + 0));
  }
  return m;
}

// ---------------- FPS: one block per batch, 512 threads, lane prune ---------
__global__ __launch_bounds__(512) void fps_kernel(const float* __restrict__ xyz,
                                                  float* __restrict__ new_xyz) {
  const int b = blockIdx.x;
  const int tid = threadIdx.x;
  const int lane = tid & 63;
  const int wid = tid >> 6;
  __shared__ float sx[NPTS], sy[NPTS], sz[NPTS];   // original order
  __shared__ unsigned short sidx16[NPTS];          // sorted pos -> orig idx
  __shared__ unsigned offs[4096];
  __shared__ unsigned wsum[8];
  __shared__ int farhist[NPOINT];
  __shared__ __align__(16) double skey[2][8];

  const float* xb = xyz + (size_t)b * NPTS * 3;
  for (int i = tid; i < NPTS; i += 512) {
    sx[i] = xb[3 * i + 0];
    sy[i] = xb[3 * i + 1];
    sz[i] = xb[3 * i + 2];
  }
  for (int i = tid; i < 4096; i += 512) offs[i] = 0;
  __syncthreads();
  for (int r = 0; r < 16; ++r) {
    int i = tid + r * 512;
    atomicAdd(&offs[morton12(cell16(sx[i]), cell16(sy[i]), cell16(sz[i]))], 1u);
  }
  __syncthreads();
  unsigned loc[8];
  unsigned s = 0;
#pragma unroll
  for (int q = 0; q < 8; ++q) {
    loc[q] = s;
    s += offs[tid * 8 + q];
  }
  unsigned inc = wave_scan_incl(s);
  if (lane == 63) wsum[wid] = inc;
  __syncthreads();
  unsigned pre = 0;
#pragma unroll
  for (int w = 0; w < 8; ++w) pre += (w < wid) ? wsum[w] : 0u;
  unsigned excl = pre + inc - s;
  __syncthreads();
#pragma unroll
  for (int q = 0; q < 8; ++q) offs[tid * 8 + q] = excl + loc[q];
  __syncthreads();
  for (int r = 0; r < 16; ++r) {
    int i = tid + r * 512;
    unsigned m = morton12(cell16(sx[i]), cell16(sy[i]), cell16(sz[i]));
    unsigned pos = atomicAdd(&offs[m], 1u);
    sidx16[pos] = (unsigned short)i;
  }
  __syncthreads();

  f32x2 px[8], py[8], pz[8];
  float dist[16];
  unsigned noid[16];  // ~origidx
  float blx = 1e30f, bhx = -1e30f, bly = 1e30f, bhy = -1e30f,
        blz = 1e30f, bhz = -1e30f;
#pragma unroll
  for (int j = 0; j < 8; ++j) {
    unsigned i0 = sidx16[tid * 16 + 2 * j], i1 = sidx16[tid * 16 + 2 * j + 1];
    noid[2 * j] = ~i0; noid[2 * j + 1] = ~i1;
    float x0 = sx[i0], x1 = sx[i1];
    float y0 = sy[i0], y1 = sy[i1];
    float z0 = sz[i0], z1 = sz[i1];
    px[j].x = x0; px[j].y = x1;
    py[j].x = y0; py[j].y = y1;
    pz[j].x = z0; pz[j].y = z1;
    blx = fminf(blx, fminf(x0, x1)); bhx = fmaxf(bhx, fmaxf(x0, x1));
    bly = fminf(bly, fminf(y0, y1)); bhy = fmaxf(bhy, fmaxf(y0, y1));
    blz = fminf(blz, fminf(z0, z1)); bhz = fmaxf(bhz, fmaxf(z0, z1));
    dist[2 * j] = 1e10f; dist[2 * j + 1] = 1e10f;
  }
  float gmaxd = 1e30f;  // forces update on iter 0
  double gkey = 0.0;
  int far = 0;
  for (int it = 0; it < NPOINT; ++it) {
    if (tid == 0) farhist[it] = far;
    const float cx = sx[far], cy = sy[far], cz = sz[far];
    float gx = fmaxf(fmaxf(blx - cx, cx - bhx), 0.f);
    float gy = fmaxf(fmaxf(bly - cy, cy - bhy), 0.f);
    float gz = fmaxf(fmaxf(blz - cz, cz - bhz), 0.f);
    float mind2 = gx * gx + gy * gy + gz * gz;
    if (mind2 * 0.999f < gmaxd) {
      f32x2 ncx, ncy, ncz;
      ncx.x = -cx; ncx.y = -cx;
      ncy.x = -cy; ncy.y = -cy;
      ncz.x = -cz; ncz.y = -cz;
      double k = 0.0;
#pragma unroll
      for (int j = 0; j < 8; ++j) {
        // exact numpy rounding: (dx^2 + dy^2) + dz^2, RN each step, no FMA
        f32x2 dx = pk_add(px[j], ncx);
        f32x2 dy = pk_add(py[j], ncy);
        f32x2 dz = pk_add(pz[j], ncz);
        f32x2 xx = pk_mul(dx, dx);
        f32x2 yy = pk_mul(dy, dy);
        f32x2 dd = pk_add(pk_add(xx, yy), pk_mul(dz, dz));
        float n0 = fminf(dist[2 * j], dd.x);
        float n1 = fminf(dist[2 * j + 1], dd.y);
        dist[2 * j] = n0; dist[2 * j + 1] = n1;
        k = kmax(k, mkkey(__float_as_uint(n0), noid[2 * j]));
        k = kmax(k, mkkey(__float_as_uint(n1), noid[2 * j + 1]));
      }
      gkey = k;
      gmaxd = __uint_as_float((unsigned)((u64)__double_as_longlong(k) >> 32));
    }
    double key = wave_max_key_d(gkey);
    const int p = it & 1;
    if (lane == 63) skey[p][wid] = key;
    __syncthreads();
    const double2* kp = (const double2*)&skey[p][0];
    double2 a0 = kp[0], a1 = kp[1], a2 = kp[2], a3 = kp[3];
    double q0 = kmax(a0.x, a0.y), q1 = kmax(a1.x, a1.y);
    double q2 = kmax(a2.x, a2.y), q3 = kmax(a3.x, a3.y);
    double best = kmax(kmax(q0, q1), kmax(q2, q3));
    far = (int)~(unsigned)(u64)__double_as_longlong(best);
  }
  __syncthreads();
  for (int t = tid; t < NPOINT; t += 512) {
    int f = farhist[t];
    float* o = new_xyz + ((size_t)b * NPOINT + t) * 3;
    o[0] = sx[f]; o[1] = sy[f]; o[2] = sz[f];
  }
}

// ---- DIAG V2: loop floor — no prune, no update, static keys ----
__global__ __launch_bounds__(512) void fps_floor(const float* __restrict__ xyz,
                                                 float* __restrict__ diag) {
  const int b = blockIdx.x;
  const int tid = threadIdx.x;
  const int lane = tid & 63;
  const int wid = tid >> 6;
  __shared__ float sx[NPTS], sy[NPTS], sz[NPTS];
  __shared__ __align__(16) double skey[2][8];
  const float* xb = xyz + (size_t)b * NPTS * 3;
  for (int i = tid; i < NPTS; i += 512) {
    sx[i] = xb[3 * i + 0]; sy[i] = xb[3 * i + 1]; sz[i] = xb[3 * i + 2];
  }
  __syncthreads();
  double gkey = mkkey(__float_as_uint(1e10f), ~(unsigned)(tid * 16));
  int far = 0;
  float sink = 0.f;
  for (int it = 0; it < NPOINT; ++it) {
    double g2 = __longlong_as_double(__double_as_longlong(gkey) ^ (long long)(it & 1));
    double key = wave_max_key_d(g2);
    const int p = it & 1;
    if (lane == 63) skey[p][wid] = key;
    __syncthreads();
    const double2* kp = (const double2*)&skey[p][0];
    double2 a0 = kp[0], a1 = kp[1], a2 = kp[2], a3 = kp[3];
    double q0 = kmax(a0.x, a0.y), q1 = kmax(a1.x, a1.y);
    double q2 = kmax(a2.x, a2.y), q3 = kmax(a3.x, a3.y);
    double best = kmax(kmax(q0, q1), kmax(q2, q3));
    far = (int)(~(unsigned)(u64)__double_as_longlong(best)) & (NPTS - 1);
    sink = fmaxf(sink, sx[far] + sy[far] + sz[far]);
  }
  if (tid == 0) diag[b] = sink + (float)far;
}

// ---- DIAG V3: update+prune cost, LCG far walk, no reduce/barrier ----
__global__ __launch_bounds__(512) void fps_nored(const float* __restrict__ xyz,
                                                 float* __restrict__ diag) {
  const int b = blockIdx.x;
  const int tid = threadIdx.x;
  const int lane = tid & 63;
  const int wid = tid >> 6;
  __shared__ float sx[NPTS], sy[NPTS], sz[NPTS];
  __shared__ unsigned short sidx16[NPTS];
  __shared__ unsigned offs[4096];
  __shared__ unsigned wsum[8];
  const float* xb = xyz + (size_t)b * NPTS * 3;
  for (int i = tid; i < NPTS; i += 512) {
    sx[i] = xb[3 * i + 0]; sy[i] = xb[3 * i + 1]; sz[i] = xb[3 * i + 2];
  }
  for (int i = tid; i < 4096; i += 512) offs[i] = 0;
  __syncthreads();
  for (int r = 0; r < 16; ++r) {
    int i = tid + r * 512;
    atomicAdd(&offs[morton12(cell16(sx[i]), cell16(sy[i]), cell16(sz[i]))], 1u);
  }
  __syncthreads();
  unsigned loc[8];
  unsigned s = 0;
#pragma unroll
  for (int q = 0; q < 8; ++q) { loc[q] = s; s += offs[tid * 8 + q]; }
  unsigned inc = wave_scan_incl(s);
  if (lane == 63) wsum[wid] = inc;
  __syncthreads();
  unsigned pre = 0;
#pragma unroll
  for (int w = 0; w < 8; ++w) pre += (w < wid) ? wsum[w] : 0u;
  unsigned excl = pre + inc - s;
  __syncthreads();
#pragma unroll
  for (int q = 0; q < 8; ++q) offs[tid * 8 + q] = excl + loc[q];
  __syncthreads();
  for (int r = 0; r < 16; ++r) {
    int i = tid + r * 512;
    unsigned m = morton12(cell16(sx[i]), cell16(sy[i]), cell16(sz[i]));
    unsigned pos = atomicAdd(&offs[m], 1u);
    sidx16[pos] = (unsigned short)i;
  }
  __syncthreads();
  f32x2 px[8], py[8], pz[8];
  float dist[16];
  unsigned noid[16];
  float blx = 1e30f, bhx = -1e30f, bly = 1e30f, bhy = -1e30f,
        blz = 1e30f, bhz = -1e30f;
#pragma unroll
  for (int j = 0; j < 8; ++j) {
    unsigned i0 = sidx16[tid * 16 + 2 * j], i1 = sidx16[tid * 16 + 2 * j + 1];
    noid[2 * j] = ~i0; noid[2 * j + 1] = ~i1;
    float x0 = sx[i0], x1 = sx[i1];
    float y0 = sy[i0], y1 = sy[i1];
    float z0 = sz[i0], z1 = sz[i1];
    px[j].x = x0; px[j].y = x1;
    py[j].x = y0; py[j].y = y1;
    pz[j].x = z0; pz[j].y = z1;
    blx = fminf(blx, fminf(x0, x1)); bhx = fmaxf(bhx, fmaxf(x0, x1));
    bly = fminf(bly, fminf(y0, y1)); bhy = fmaxf(bhy, fmaxf(y0, y1));
    blz = fminf(blz, fminf(z0, z1)); bhz = fmaxf(bhz, fmaxf(z0, z1));
    dist[2 * j] = 1e10f; dist[2 * j + 1] = 1e10f;
  }
  float gmaxd = 1e30f;
  double gkey = 0.0;
  unsigned far = 0;
  for (int it = 0; it < NPOINT; ++it) {
    const float cx = sx[far], cy = sy[far], cz = sz[far];
    float gx = fmaxf(fmaxf(blx - cx, cx - bhx), 0.f);
    float gy = fmaxf(fmaxf(bly - cy, cy - bhy), 0.f);
    float gz = fmaxf(fmaxf(blz - cz, cz - bhz), 0.f);
    float mind2 = gx * gx + gy * gy + gz * gz;
    if (mind2 * 0.999f < gmaxd) {
      f32x2 ncx, ncy, ncz;
      ncx.x = -cx; ncx.y = -cx;
      ncy.x = -cy; ncy.y = -cy;
      ncz.x = -cz; ncz.y = -cz;
      double k = 0.0;
#pragma unroll
      for (int j = 0; j < 8; ++j) {
        f32x2 dx = pk_add(px[j], ncx);
        f32x2 dy = pk_add(py[j], ncy);
        f32x2 dz = pk_add(pz[j], ncz);
        f32x2 xx = pk_mul(dx, dx);
        f32x2 yy = pk_mul(dy, dy);
        f32x2 dd = pk_add(pk_add(xx, yy), pk_mul(dz, dz));
        float n0 = fminf(dist[2 * j], dd.x);
        float n1 = fminf(dist[2 * j + 1], dd.y);
        dist[2 * j] = n0; dist[2 * j + 1] = n1;
        k = kmax(k, mkkey(__float_as_uint(n0), noid[2 * j]));
        k = kmax(k, mkkey(__float_as_uint(n1), noid[2 * j + 1]));
      }
      gkey = kmax(gkey, k);
      gmaxd = __uint_as_float((unsigned)((u64)__double_as_longlong(k) >> 32));
    }
    far = (far * 1664525u + 1013904223u) & (NPTS - 1);  // deterministic walk
  }
  // keep everything live
  double t = wave_max_key_d(gkey);
  if (lane == 63) diag[b * 8 + wid] = (float)t + sx[far];
}

// ---------------- feature transpose (B,C,N) -> (B,N,C) ----------------
__global__ __launch_bounds__(256) void tr_kernel(const float* __restrict__ f,
                                                 float* __restrict__ ft) {
  int idx = blockIdx.x * 256 + threadIdx.x;
  int c = idx & 63;
  int i = (idx >> 6) & (NPTS - 1);
  int b = idx >> 19;
  ft[idx] = f[((size_t)(b * CF + c)) * NPTS + i];
}

// ---------------- ball query: one wave per center ----------------
__global__ __launch_bounds__(256) void bq_kernel(const float* __restrict__ xyz,
                                                 const float* __restrict__ new_xyz,
                                                 int* __restrict__ idxbuf) {
  const int lane = threadIdx.x & 63;
  const int gw = (blockIdx.x * 256 + threadIdx.x) >> 6;
  const int b = gw >> 11;
  const int j = gw & 2047;
  const float* xb = xyz + (size_t)b * NPTS * 3;
  const float* c = new_xyz + ((size_t)b * NPOINT + j) * 3;
  const float cx = c[0], cy = c[1], cz = c[2];
  int* out = idxbuf + ((size_t)b * NPOINT + j) * NSAMPLE;
  const float r2 = 0.01f;
  int found = 0, first = 0;
  for (int base = 0; base < NPTS && found < NSAMPLE; base += 64) {
    const int i = base + lane;
    float dx = xb[3 * i + 0] - cx, dy = xb[3 * i + 1] - cy, dz = xb[3 * i + 2] - cz;
    float d = __fadd_rn(__fadd_rn(__fmul_rn(dx, dx), __fmul_rn(dy, dy)),
                        __fmul_rn(dz, dz));
    bool in = (d <= r2);
    unsigned long long mask = __ballot(in);
    if (mask) {
      if (found == 0) first = base + (__ffsll(mask) - 1);
      int slot = found + __popcll(mask & ((1ull << lane) - 1ull));
      if (in && slot < NSAMPLE) out[slot] = i;
      found += (int)__popcll(mask);
    }
  }
  for (int s = found + lane; s < NSAMPLE; s += 64) out[s] = first;
}

// ---------------- fused gather + MLP + max ----------------
__global__ __launch_bounds__(256) void mlp_kernel(const float* __restrict__ xyz,
                                                  const float* __restrict__ ft,
                                                  const float* __restrict__ feat,
                                                  const int* __restrict__ idxbuf,
                                                  const float* __restrict__ new_xyz,
                                                  const float* __restrict__ W0,
                                                  const float* __restrict__ b0,
                                                  const float* __restrict__ W1,
                                                  const float* __restrict__ b1,
                                                  const float* __restrict__ W2,
                                                  const float* __restrict__ b2,
                                                  float* __restrict__ out_nf,
                                                  int use_ft) {
  __shared__ __align__(16) float Ws0[CIN * 64];   // [c][o]
  __shared__ __align__(16) float Ws1[64 * 64];    // [c][o]
  __shared__ __align__(16) float Ws2[64 * 128];   // [c][o]
  __shared__ float bs0[64], bs1[64], bs2[128];
  __shared__ __align__(16) float X0[CIN * 32];    // [c][k]
  __shared__ __align__(16) float X1[64 * 32];     // [c][k]
  const int tid = threadIdx.x;
  const int k = tid & 31;
  const int og = tid >> 5;  // 0..7
  for (int t = tid; t < 64 * CIN; t += 256) {
    int o = t / CIN, c = t - o * CIN;
    Ws0[c * 64 + o] = W0[t];
  }
  for (int t = tid; t < 64 * 64; t += 256) Ws1[(t & 63) * 64 + (t >> 6)] = W1[t];
  for (int t = tid; t < 128 * 64; t += 256) Ws2[(t & 63) * 128 + (t >> 6)] = W2[t];
  if (tid < 64) { bs0[tid] = b0[tid]; bs1[tid] = b1[tid]; }
  if (tid < 128) bs2[tid] = b2[tid];
  __syncthreads();

  for (int g = 0; g < G; ++g) {
    const int cj = blockIdx.x * G + g;
    const int b = cj >> 11;
    const int j = cj & 2047;
    const int ni = idxbuf[cj * NSAMPLE + k];
    if (og == 0) {
      const float* ctr = new_xyz + (size_t)cj * 3;
      const float* pp = xyz + ((size_t)b * NPTS + ni) * 3;
      X0[0 * 32 + k] = pp[0] - ctr[0];
      X0[1 * 32 + k] = pp[1] - ctr[1];
      X0[2 * 32 + k] = pp[2] - ctr[2];
    }
    const int cbase = 3 + og * 8;
    if (use_ft) {
      const float4* fr = (const float4*)(ft + ((size_t)b * NPTS + ni) * CF + og * 8);
      float4 f0 = fr[0], f1 = fr[1];
      X0[(cbase + 0) * 32 + k] = f0.x; X0[(cbase + 1) * 32 + k] = f0.y;
      X0[(cbase + 2) * 32 + k] = f0.z; X0[(cbase + 3) * 32 + k] = f0.w;
      X0[(cbase + 4) * 32 + k] = f1.x; X0[(cbase + 5) * 32 + k] = f1.y;
      X0[(cbase + 6) * 32 + k] = f1.z; X0[(cbase + 7) * 32 + k] = f1.w;
    } else {
      const float* fb = feat + (size_t)b * CF * NPTS + ni;
#pragma unroll
      for (int q = 0; q < 8; ++q)
        X0[(cbase + q) * 32 + k] = fb[(size_t)(og * 8 + q) * NPTS];
    }
    __syncthreads();

    // L0: 67 -> 64
    float acc[8];
#pragma unroll
    for (int i = 0; i < 8; ++i) acc[i] = bs0[og * 8 + i];
    for (int c = 0; c < CIN; ++c) {
      float xv = X0[c * 32 + k];
      const float4* wr = (const float4*)&Ws0[c * 64 + og * 8];
      float4 w0 = wr[0], w1 = wr[1];
      acc[0] = fmaf(w0.x, xv, acc[0]); acc[1] = fmaf(w0.y, xv, acc[1]);
      acc[2] = fmaf(w0.z, xv, acc[2]); acc[3] = fmaf(w0.w, xv, acc[3]);
      acc[4] = fmaf(w1.x, xv, acc[4]); acc[5] = fmaf(w1.y, xv, acc[5]);
      acc[6] = fmaf(w1.z, xv, acc[6]); acc[7] = fmaf(w1.w, xv, acc[7]);
    }
#pragma unroll
    for (int i = 0; i < 8; ++i) X1[(og * 8 + i) * 32 + k] = fmaxf(acc[i], 0.f);
    __syncthreads();

    // L1: 64 -> 64 (reads X1, writes X0)
    float a1[8];
#pragma unroll
    for (int i = 0; i < 8; ++i) a1[i] = bs1[og * 8 + i];
    for (int c = 0; c < 64; ++c) {
      float xv = X1[c * 32 + k];
      const float4* wr = (const float4*)&Ws1[c * 64 + og * 8];
      float4 w0 = wr[0], w1 = wr[1];
      a1[0] = fmaf(w0.x, xv, a1[0]); a1[1] = fmaf(w0.y, xv, a1[1]);
      a1[2] = fmaf(w0.z, xv, a1[2]); a1[3] = fmaf(w0.w, xv, a1[3]);
      a1[4] = fmaf(w1.x, xv, a1[4]); a1[5] = fmaf(w1.y, xv, a1[5]);
      a1[6] = fmaf(w1.z, xv, a1[6]); a1[7] = fmaf(w1.w, xv, a1[7]);
    }
#pragma unroll
    for (int i = 0; i < 8; ++i) X0[(og * 8 + i) * 32 + k] = fmaxf(a1[i], 0.f);
    __syncthreads();

    // L2: 64 -> 128 (reads X0 rows 0..63), fused relu + max over k
    float a2[16];
#pragma unroll
    for (int i = 0; i < 16; ++i) a2[i] = bs2[og * 16 + i];
    for (int c = 0; c < 64; ++c) {
      float xv = X0[c * 32 + k];
      const float4* wr = (const float4*)&Ws2[c * 128 + og * 16];
      float4 w0 = wr[0], w1 = wr[1], w2 = wr[2], w3 = wr[3];
      a2[0]  = fmaf(w0.x, xv, a2[0]);  a2[1]  = fmaf(w0.y, xv, a2[1]);
      a2[2]  = fmaf(w0.z, xv, a2[2]);  a2[3]  = fmaf(w0.w, xv, a2[3]);
      a2[4]  = fmaf(w1.x, xv, a2[4]);  a2[5]  = fmaf(w1.y, xv, a2[5]);
      a2[6]  = fmaf(w1.z, xv, a2[6]);  a2[7]  = fmaf(w1.w, xv, a2[7]);
      a2[8]  = fmaf(w2.x, xv, a2[8]);  a2[9]  = fmaf(w2.y, xv, a2[9]);
      a2[10] = fmaf(w2.z, xv, a2[10]); a2[11] = fmaf(w2.w, xv, a2[11]);
      a2[12] = fmaf(w3.x, xv, a2[12]); a2[13] = fmaf(w3.y, xv, a2[13]);
      a2[14] = fmaf(w3.z, xv, a2[14]); a2[15] = fmaf(w3.w, xv, a2[15]);
    }
#pragma unroll
    for (int i = 0; i < 16; ++i) {
      float v = fmaxf(a2[i], 0.f);
#pragma unroll
      for (int m = 1; m < 32; m <<= 1) v = fmaxf(v, __shfl_xor(v, m));
      a2[i] = v;
    }
    if (k == 0) {
#pragma unroll
      for (int i = 0; i < 16; ++i)
        out_nf[((size_t)b * 128 + og * 16 + i) * NPOINT + j] = a2[i];
    }
    __syncthreads();
  }
}

extern "C" void kernel_launch(void* const* d_in, const int* in_sizes, int n_in,
                              void* d_out, int out_size, void* d_ws, size_t ws_size,
                              hipStream_t stream) {
  (void)in_sizes; (void)n_in; (void)out_size;
  const float* xyz  = (const float*)d_in[0];
  const float* feat = (const float*)d_in[1];
  const float* W0   = (const float*)d_in[2];
  const float* b0   = (const float*)d_in[3];
  const float* W1   = (const float*)d_in[4];
  const float* b1   = (const float*)d_in[5];
  const float* W2   = (const float*)d_in[6];
  const float* b2   = (const float*)d_in[7];
  float* new_xyz = (float*)d_out;
  float* out_nf  = (float*)d_out + (size_t)NB * NPOINT * 3;

  int* idxbuf = (int*)d_ws;
  size_t idx_bytes = (size_t)NB * NPOINT * NSAMPLE * sizeof(int);
  float* ft = (float*)((char*)d_ws + idx_bytes);
  size_t need = idx_bytes + (size_t)NB * NPTS * CF * sizeof(float);
  int use_ft = (ws_size >= need) ? 1 : 0;
  float* diag = (float*)((char*)d_ws + need);
  int use_diag = (ws_size >= need + 65536) ? 1 : 0;

  fps_kernel<<<NB, 512, 0, stream>>>(xyz, new_xyz);
  if (use_ft) tr_kernel<<<(NB * NPTS * CF) / 256, 256, 0, stream>>>(feat, ft);
  bq_kernel<<<(NB * NPOINT) / 4, 256, 0, stream>>>(xyz, new_xyz, idxbuf);
  mlp_kernel<<<(NB * NPOINT) / G, 256, 0, stream>>>(xyz, ft, feat, idxbuf, new_xyz,
                                                    W0, b0, W1, b1, W2, b2,
                                                    out_nf, use_ft);
  if (use_diag) {
    fps_floor<<<NB, 512, 0, stream>>>(xyz, diag);
    fps_nored<<<NB, 512, 0, stream>>>(xyz, diag + 1024);
  }
}

// Round 11
// 2570.305 us; speedup vs baseline: 1.3097x; 1.3097x over previous
//
#include <hip/hip_runtime.h>

#define NB 4
#define NPTS 8192
#define NPOINT 2048
#define NSAMPLE 32
#define CF 64      // feature channels
#define CIN 67     // 3 + 64
#define G 8        // centers per MLP block

typedef float f32x2 __attribute__((ext_vector_type(2)));
typedef unsigned long long u64;

__device__ __forceinline__ f32x2 pk_add(f32x2 a, f32x2 b) {
  f32x2 d;
  asm("v_pk_add_f32 %0, %1, %2" : "=v"(d) : "v"(a), "v"(b));
  return d;
}
__device__ __forceinline__ f32x2 pk_mul(f32x2 a, f32x2 b) {
  f32x2 d;
  asm("v_pk_mul_f32 %0, %1, %2" : "=v"(d) : "v"(a), "v"(b));
  return d;
}

template <int CTRL, int RM>
__device__ __forceinline__ int dppi(int v) {
  return __builtin_amdgcn_update_dpp(0, v, CTRL, RM, 0xf, true);
}
// key = (f32 dist bits << 32) | ~origidx, always < 0x7FF0.. as u64 ->
// positive double whose IEEE order == u64 order. One v_max_f64 per merge.
__device__ __forceinline__ double kmax(double a, double b) { return fmax(a, b); }
__device__ __forceinline__ double mkkey(unsigned hi, unsigned lo) {
  return __longlong_as_double(((long long)hi << 32) | lo);
}
template <int CTRL, int RM>
__device__ __forceinline__ double kstep_d(double k) {
  long long bb = __double_as_longlong(k);
  unsigned lo = (unsigned)bb, hi = (unsigned)(bb >> 32);
  unsigned olo = (unsigned)dppi<CTRL, RM>((int)lo);
  unsigned ohi = (unsigned)dppi<CTRL, RM>((int)hi);
  double o = __longlong_as_double(((long long)ohi << 32) | olo);
  return fmax(k, o);
}
__device__ __forceinline__ double wave_max_key_d(double key) {
  key = kstep_d<0x111, 0xf>(key);  // row_shr:1
  key = kstep_d<0x112, 0xf>(key);  // row_shr:2
  key = kstep_d<0x114, 0xf>(key);  // row_shr:4
  key = kstep_d<0x118, 0xf>(key);  // row_shr:8
  key = kstep_d<0x142, 0xa>(key);  // row_bcast:15
  key = kstep_d<0x143, 0xc>(key);  // row_bcast:31
  return key;
}
// wave-64 inclusive add-scan (valid all lanes; lane63 = total)
__device__ __forceinline__ unsigned wave_scan_incl(unsigned v) {
  v += (unsigned)__builtin_amdgcn_update_dpp(0, (int)v, 0x111, 0xf, 0xf, true);
  v += (unsigned)__builtin_amdgcn_update_dpp(0, (int)v, 0x112, 0xf, 0xf, true);
  v += (unsigned)__builtin_amdgcn_update_dpp(0, (int)v, 0x114, 0xf, 0xf, true);
  v += (unsigned)__builtin_amdgcn_update_dpp(0, (int)v, 0x118, 0xf, 0xf, true);
  v += (unsigned)__builtin_amdgcn_update_dpp(0, (int)v, 0x142, 0xa, 0xf, true);
  v += (unsigned)__builtin_amdgcn_update_dpp(0, (int)v, 0x143, 0xc, 0xf, true);
  return v;
}

__device__ __forceinline__ int cell16(float x) {
  int c = (int)(x * 16.0f);
  return c > 15 ? 15 : (c < 0 ? 0 : c);
}
__device__ __forceinline__ unsigned morton12(int ix, int iy, int iz) {
  unsigned m = 0;
#pragma unroll
  for (int k = 0; k < 4; ++k) {
    m |= ((unsigned)((ix >> k) & 1) << (3 * k + 2)) |
         ((unsigned)((iy >> k) & 1) << (3 * k + 1)) |
         ((unsigned)((iz >> k) & 1) << (3 * k + 0));
  }
  return m;
}

// 16-point register-resident subgroup with AABB + cached (key, maxdist)
struct SubGrp {
  f32x2 px[8], py[8], pz[8];
  float dist[16];
  unsigned noid[16];
  float blx, bhx, bly, bhy, blz, bhz;
  double skey;   // cached max key over the subgroup
  float gmaxd;   // hi word of skey as float

  __device__ __forceinline__ void load(const unsigned short* sidx16,
                                       const float* sx, const float* sy,
                                       const float* sz, int base) {
    blx = 1e30f; bhx = -1e30f; bly = 1e30f; bhy = -1e30f;
    blz = 1e30f; bhz = -1e30f;
#pragma unroll
    for (int j = 0; j < 8; ++j) {
      unsigned i0 = sidx16[base + 2 * j], i1 = sidx16[base + 2 * j + 1];
      noid[2 * j] = ~i0; noid[2 * j + 1] = ~i1;
      float x0 = sx[i0], x1 = sx[i1];
      float y0 = sy[i0], y1 = sy[i1];
      float z0 = sz[i0], z1 = sz[i1];
      px[j].x = x0; px[j].y = x1;
      py[j].x = y0; py[j].y = y1;
      pz[j].x = z0; pz[j].y = z1;
      blx = fminf(blx, fminf(x0, x1)); bhx = fmaxf(bhx, fmaxf(x0, x1));
      bly = fminf(bly, fminf(y0, y1)); bhy = fmaxf(bhy, fmaxf(y0, y1));
      blz = fminf(blz, fminf(z0, z1)); bhz = fmaxf(bhz, fmaxf(z0, z1));
      dist[2 * j] = 1e10f; dist[2 * j + 1] = 1e10f;
    }
    skey = 0.0;
    gmaxd = 1e30f;  // force update on iter 0
  }

  // returns true if this subgroup may change for centroid c (exact prune)
  __device__ __forceinline__ bool dirty(float cx, float cy, float cz) const {
    float gx = fmaxf(fmaxf(blx - cx, cx - bhx), 0.f);
    float gy = fmaxf(fmaxf(bly - cy, cy - bhy), 0.f);
    float gz = fmaxf(fmaxf(blz - cz, cz - bhz), 0.f);
    float mind2 = gx * gx + gy * gy + gz * gz;
    return mind2 * 0.999f < gmaxd;
  }

  __device__ __forceinline__ void update(float cx, float cy, float cz) {
    f32x2 ncx, ncy, ncz;
    ncx.x = -cx; ncx.y = -cx;
    ncy.x = -cy; ncy.y = -cy;
    ncz.x = -cz; ncz.y = -cz;
    double k = 0.0;
#pragma unroll
    for (int j = 0; j < 8; ++j) {
      // exact numpy rounding: (dx^2 + dy^2) + dz^2, RN each step, no FMA
      f32x2 dx = pk_add(px[j], ncx);
      f32x2 dy = pk_add(py[j], ncy);
      f32x2 dz = pk_add(pz[j], ncz);
      f32x2 xx = pk_mul(dx, dx);
      f32x2 yy = pk_mul(dy, dy);
      f32x2 dd = pk_add(pk_add(xx, yy), pk_mul(dz, dz));
      float n0 = fminf(dist[2 * j], dd.x);
      float n1 = fminf(dist[2 * j + 1], dd.y);
      dist[2 * j] = n0; dist[2 * j + 1] = n1;
      k = kmax(k, mkkey(__float_as_uint(n0), noid[2 * j]));
      k = kmax(k, mkkey(__float_as_uint(n1), noid[2 * j + 1]));
    }
    skey = k;
    gmaxd = __uint_as_float((unsigned)((u64)__double_as_longlong(k) >> 32));
  }
};

// ---- FPS: one block per batch, 256 threads (4 waves, 1/SIMD), lane prune ---
__global__ __launch_bounds__(256) void fps_kernel(const float* __restrict__ xyz,
                                                  float* __restrict__ new_xyz) {
  const int b = blockIdx.x;
  const int tid = threadIdx.x;
  const int lane = tid & 63;
  const int wid = tid >> 6;
  __shared__ float sx[NPTS], sy[NPTS], sz[NPTS];   // original order
  __shared__ unsigned short sidx16[NPTS];          // sorted pos -> orig idx
  __shared__ unsigned offs[4096];
  __shared__ unsigned wsum[4];
  __shared__ int farhist[NPOINT];
  __shared__ __align__(16) double skey[2][4];

  const float* xb = xyz + (size_t)b * NPTS * 3;
  for (int i = tid; i < NPTS; i += 256) {
    sx[i] = xb[3 * i + 0];
    sy[i] = xb[3 * i + 1];
    sz[i] = xb[3 * i + 2];
  }
  for (int i = tid; i < 4096; i += 256) offs[i] = 0;
  __syncthreads();
  // histogram over 4096 morton bins
  for (int r = 0; r < 32; ++r) {
    int i = tid + r * 256;
    atomicAdd(&offs[morton12(cell16(sx[i]), cell16(sy[i]), cell16(sz[i]))], 1u);
  }
  __syncthreads();
  // block exclusive scan of 4096 bins (16 per thread)
  unsigned loc[16];
  unsigned s = 0;
#pragma unroll
  for (int q = 0; q < 16; ++q) {
    loc[q] = s;
    s += offs[tid * 16 + q];
  }
  unsigned inc = wave_scan_incl(s);
  if (lane == 63) wsum[wid] = inc;
  __syncthreads();
  unsigned pre = 0;
#pragma unroll
  for (int w = 0; w < 4; ++w) pre += (w < wid) ? wsum[w] : 0u;
  unsigned excl = pre + inc - s;
  __syncthreads();
#pragma unroll
  for (int q = 0; q < 16; ++q) offs[tid * 16 + q] = excl + loc[q];
  __syncthreads();
  // scatter original indices into morton order
  for (int r = 0; r < 32; ++r) {
    int i = tid + r * 256;
    unsigned m = morton12(cell16(sx[i]), cell16(sy[i]), cell16(sz[i]));
    unsigned pos = atomicAdd(&offs[m], 1u);
    sidx16[pos] = (unsigned short)i;
  }
  __syncthreads();

  // thread owns 32 consecutive morton-sorted points as two 16-pt subgroups
  SubGrp A, B;
  A.load(sidx16, sx, sy, sz, tid * 32);
  B.load(sidx16, sx, sy, sz, tid * 32 + 16);

  int far = 0;
  for (int it = 0; it < NPOINT; ++it) {
    if (tid == 0) farhist[it] = far;
    const float cx = sx[far], cy = sy[far], cz = sz[far];
    bool da = A.dirty(cx, cy, cz);
    if (__ballot(da)) {
      if (da) A.update(cx, cy, cz);
    }
    bool db = B.dirty(cx, cy, cz);
    if (__ballot(db)) {
      if (db) B.update(cx, cy, cz);
    }
    double key = wave_max_key_d(kmax(A.skey, B.skey));
    const int p = it & 1;
    if (lane == 63) skey[p][wid] = key;
    __syncthreads();
    const double2* kp = (const double2*)&skey[p][0];
    double2 a0 = kp[0], a1 = kp[1];
    double best = kmax(kmax(a0.x, a0.y), kmax(a1.x, a1.y));
    far = (int)~(unsigned)(u64)__double_as_longlong(best);
  }
  __syncthreads();
  for (int t = tid; t < NPOINT; t += 256) {
    int f = farhist[t];
    float* o = new_xyz + ((size_t)b * NPOINT + t) * 3;
    o[0] = sx[f]; o[1] = sy[f]; o[2] = sz[f];
  }
}

// ---------------- feature transpose (B,C,N) -> (B,N,C) ----------------
__global__ __launch_bounds__(256) void tr_kernel(const float* __restrict__ f,
                                                 float* __restrict__ ft) {
  int idx = blockIdx.x * 256 + threadIdx.x;
  int c = idx & 63;
  int i = (idx >> 6) & (NPTS - 1);
  int b = idx >> 19;
  ft[idx] = f[((size_t)(b * CF + c)) * NPTS + i];
}

// ---------------- ball query: one wave per center ----------------
__global__ __launch_bounds__(256) void bq_kernel(const float* __restrict__ xyz,
                                                 const float* __restrict__ new_xyz,
                                                 int* __restrict__ idxbuf) {
  const int lane = threadIdx.x & 63;
  const int gw = (blockIdx.x * 256 + threadIdx.x) >> 6;
  const int b = gw >> 11;
  const int j = gw & 2047;
  const float* xb = xyz + (size_t)b * NPTS * 3;
  const float* c = new_xyz + ((size_t)b * NPOINT + j) * 3;
  const float cx = c[0], cy = c[1], cz = c[2];
  int* out = idxbuf + ((size_t)b * NPOINT + j) * NSAMPLE;
  const float r2 = 0.01f;
  int found = 0, first = 0;
  for (int base = 0; base < NPTS && found < NSAMPLE; base += 64) {
    const int i = base + lane;
    float dx = xb[3 * i + 0] - cx, dy = xb[3 * i + 1] - cy, dz = xb[3 * i + 2] - cz;
    float d = __fadd_rn(__fadd_rn(__fmul_rn(dx, dx), __fmul_rn(dy, dy)),
                        __fmul_rn(dz, dz));
    bool in = (d <= r2);
    unsigned long long mask = __ballot(in);
    if (mask) {
      if (found == 0) first = base + (__ffsll(mask) - 1);
      int slot = found + __popcll(mask & ((1ull << lane) - 1ull));
      if (in && slot < NSAMPLE) out[slot] = i;
      found += (int)__popcll(mask);
    }
  }
  for (int s = found + lane; s < NSAMPLE; s += 64) out[s] = first;
}

// ---------------- fused gather + MLP + max ----------------
__global__ __launch_bounds__(256) void mlp_kernel(const float* __restrict__ xyz,
                                                  const float* __restrict__ ft,
                                                  const float* __restrict__ feat,
                                                  const int* __restrict__ idxbuf,
                                                  const float* __restrict__ new_xyz,
                                                  const float* __restrict__ W0,
                                                  const float* __restrict__ b0,
                                                  const float* __restrict__ W1,
                                                  const float* __restrict__ b1,
                                                  const float* __restrict__ W2,
                                                  const float* __restrict__ b2,
                                                  float* __restrict__ out_nf,
                                                  int use_ft) {
  __shared__ __align__(16) float Ws0[CIN * 64];   // [c][o]
  __shared__ __align__(16) float Ws1[64 * 64];    // [c][o]
  __shared__ __align__(16) float Ws2[64 * 128];   // [c][o]
  __shared__ float bs0[64], bs1[64], bs2[128];
  __shared__ __align__(16) float X0[CIN * 32];    // [c][k]
  __shared__ __align__(16) float X1[64 * 32];     // [c][k]
  const int tid = threadIdx.x;
  const int k = tid & 31;
  const int og = tid >> 5;  // 0..7
  for (int t = tid; t < 64 * CIN; t += 256) {
    int o = t / CIN, c = t - o * CIN;
    Ws0[c * 64 + o] = W0[t];
  }
  for (int t = tid; t < 64 * 64; t += 256) Ws1[(t & 63) * 64 + (t >> 6)] = W1[t];
  for (int t = tid; t < 128 * 64; t += 256) Ws2[(t & 63) * 128 + (t >> 6)] = W2[t];
  if (tid < 64) { bs0[tid] = b0[tid]; bs1[tid] = b1[tid]; }
  if (tid < 128) bs2[tid] = b2[tid];
  __syncthreads();

  for (int g = 0; g < G; ++g) {
    const int cj = blockIdx.x * G + g;
    const int b = cj >> 11;
    const int j = cj & 2047;
    const int ni = idxbuf[cj * NSAMPLE + k];
    if (og == 0) {
      const float* ctr = new_xyz + (size_t)cj * 3;
      const float* pp = xyz + ((size_t)b * NPTS + ni) * 3;
      X0[0 * 32 + k] = pp[0] - ctr[0];
      X0[1 * 32 + k] = pp[1] - ctr[1];
      X0[2 * 32 + k] = pp[2] - ctr[2];
    }
    const int cbase = 3 + og * 8;
    if (use_ft) {
      const float4* fr = (const float4*)(ft + ((size_t)b * NPTS + ni) * CF + og * 8);
      float4 f0 = fr[0], f1 = fr[1];
      X0[(cbase + 0) * 32 + k] = f0.x; X0[(cbase + 1) * 32 + k] = f0.y;
      X0[(cbase + 2) * 32 + k] = f0.z; X0[(cbase + 3) * 32 + k] = f0.w;
      X0[(cbase + 4) * 32 + k] = f1.x; X0[(cbase + 5) * 32 + k] = f1.y;
      X0[(cbase + 6) * 32 + k] = f1.z; X0[(cbase + 7) * 32 + k] = f1.w;
    } else {
      const float* fb = feat + (size_t)b * CF * NPTS + ni;
#pragma unroll
      for (int q = 0; q < 8; ++q)
        X0[(cbase + q) * 32 + k] = fb[(size_t)(og * 8 + q) * NPTS];
    }
    __syncthreads();

    // L0: 67 -> 64
    float acc[8];
#pragma unroll
    for (int i = 0; i < 8; ++i) acc[i] = bs0[og * 8 + i];
    for (int c = 0; c < CIN; ++c) {
      float xv = X0[c * 32 + k];
      const float4* wr = (const float4*)&Ws0[c * 64 + og * 8];
      float4 w0 = wr[0], w1 = wr[1];
      acc[0] = fmaf(w0.x, xv, acc[0]); acc[1] = fmaf(w0.y, xv, acc[1]);
      acc[2] = fmaf(w0.z, xv, acc[2]); acc[3] = fmaf(w0.w, xv, acc[3]);
      acc[4] = fmaf(w1.x, xv, acc[4]); acc[5] = fmaf(w1.y, xv, acc[5]);
      acc[6] = fmaf(w1.z, xv, acc[6]); acc[7] = fmaf(w1.w, xv, acc[7]);
    }
#pragma unroll
    for (int i = 0; i < 8; ++i) X1[(og * 8 + i) * 32 + k] = fmaxf(acc[i], 0.f);
    __syncthreads();

    // L1: 64 -> 64 (reads X1, writes X0)
    float a1[8];
#pragma unroll
    for (int i = 0; i < 8; ++i) a1[i] = bs1[og * 8 + i];
    for (int c = 0; c < 64; ++c) {
      float xv = X1[c * 32 + k];
      const float4* wr = (const float4*)&Ws1[c * 64 + og * 8];
      float4 w0 = wr[0], w1 = wr[1];
      a1[0] = fmaf(w0.x, xv, a1[0]); a1[1] = fmaf(w0.y, xv, a1[1]);
      a1[2] = fmaf(w0.z, xv, a1[2]); a1[3] = fmaf(w0.w, xv, a1[3]);
      a1[4] = fmaf(w1.x, xv, a1[4]); a1[5] = fmaf(w1.y, xv, a1[5]);
      a1[6] = fmaf(w1.z, xv, a1[6]); a1[7] = fmaf(w1.w, xv, a1[7]);
    }
#pragma unroll
    for (int i = 0; i < 8; ++i) X0[(og * 8 + i) * 32 + k] = fmaxf(a1[i], 0.f);
    __syncthreads();

    // L2: 64 -> 128 (reads X0 rows 0..63), fused relu + max over k
    float a2[16];
#pragma unroll
    for (int i = 0; i < 16; ++i) a2[i] = bs2[og * 16 + i];
    for (int c = 0; c < 64; ++c) {
      float xv = X0[c * 32 + k];
      const float4* wr = (const float4*)&Ws2[c * 128 + og * 16];
      float4 w0 = wr[0], w1 = wr[1], w2 = wr[2], w3 = wr[3];
      a2[0]  = fmaf(w0.x, xv, a2[0]);  a2[1]  = fmaf(w0.y, xv, a2[1]);
      a2[2]  = fmaf(w0.z, xv, a2[2]);  a2[3]  = fmaf(w0.w, xv, a2[3]);
      a2[4]  = fmaf(w1.x, xv, a2[4]);  a2[5]  = fmaf(w1.y, xv, a2[5]);
      a2[6]  = fmaf(w1.z, xv, a2[6]);  a2[7]  = fmaf(w1.w, xv, a2[7]);
      a2[8]  = fmaf(w2.x, xv, a2[8]);  a2[9]  = fmaf(w2.y, xv, a2[9]);
      a2[10] = fmaf(w2.z, xv, a2[10]); a2[11] = fmaf(w2.w, xv, a2[11]);
      a2[12] = fmaf(w3.x, xv, a2[12]); a2[13] = fmaf(w3.y, xv, a2[13]);
      a2[14] = fmaf(w3.z, xv, a2[14]); a2[15] = fmaf(w3.w, xv, a2[15]);
    }
#pragma unroll
    for (int i = 0; i < 16; ++i) {
      float v = fmaxf(a2[i], 0.f);
#pragma unroll
      for (int m = 1; m < 32; m <<= 1) v = fmaxf(v, __shfl_xor(v, m));
      a2[i] = v;
    }
    if (k == 0) {
#pragma unroll
      for (int i = 0; i < 16; ++i)
        out_nf[((size_t)b * 128 + og * 16 + i) * NPOINT + j] = a2[i];
    }
    __syncthreads();
  }
}

extern "C" void kernel_launch(void* const* d_in, const int* in_sizes, int n_in,
                              void* d_out, int out_size, void* d_ws, size_t ws_size,
                              hipStream_t stream) {
  (void)in_sizes; (void)n_in; (void)out_size;
  const float* xyz  = (const float*)d_in[0];
  const float* feat = (const float*)d_in[1];
  const float* W0   = (const float*)d_in[2];
  const float* b0   = (const float*)d_in[3];
  const float* W1   = (const float*)d_in[4];
  const float* b1   = (const float*)d_in[5];
  const float* W2   = (const float*)d_in[6];
  const float* b2   = (const float*)d_in[7];
  float* new_xyz = (float*)d_out;
  float* out_nf  = (float*)d_out + (size_t)NB * NPOINT * 3;

  int* idxbuf = (int*)d_ws;
  size_t idx_bytes = (size_t)NB * NPOINT * NSAMPLE * sizeof(int);
  float* ft = (float*)((char*)d_ws + idx_bytes);
  size_t need = idx_bytes + (size_t)NB * NPTS * CF * sizeof(float);
  int use_ft = (ws_size >= need) ? 1 : 0;

  fps_kernel<<<NB, 256, 0, stream>>>(xyz, new_xyz);
  if (use_ft) tr_kernel<<<(NB * NPTS * CF) / 256, 256, 0, stream>>>(feat, ft);
  bq_kernel<<<(NB * NPOINT) / 4, 256, 0, stream>>>(xyz, new_xyz, idxbuf);
  mlp_kernel<<<(NB * NPOINT) / G, 256, 0, stream>>>(xyz, ft, feat, idxbuf, new_xyz,
                                                    W0, b0, W1, b1, W2, b2,
                                                    out_nf, use_ft);
}

// Round 12
// 1988.449 us; speedup vs baseline: 1.6929x; 1.2926x over previous
//
#include <hip/hip_runtime.h>

#define NB 4
#define NPTS 8192
#define NPOINT 2048
#define NSAMPLE 32
#define CF 64      // feature channels
#define CIN 67     // 3 + 64
#define G 8        // centers per MLP block

typedef float f32x2 __attribute__((ext_vector_type(2)));
typedef unsigned long long u64;

__device__ __forceinline__ f32x2 pk_add(f32x2 a, f32x2 b) {
  f32x2 d;
  asm("v_pk_add_f32 %0, %1, %2" : "=v"(d) : "v"(a), "v"(b));
  return d;
}
__device__ __forceinline__ f32x2 pk_mul(f32x2 a, f32x2 b) {
  f32x2 d;
  asm("v_pk_mul_f32 %0, %1, %2" : "=v"(d) : "v"(a), "v"(b));
  return d;
}

template <int CTRL, int RM>
__device__ __forceinline__ int dppi(int v) {
  return __builtin_amdgcn_update_dpp(0, v, CTRL, RM, 0xf, true);
}
// key = (f32 dist bits << 32) | ~origidx, always < 0x7FF0.. as u64 ->
// positive double whose IEEE order == u64 order. One v_max_f64 per merge.
__device__ __forceinline__ double kmax(double a, double b) { return fmax(a, b); }
__device__ __forceinline__ double mkkey(unsigned hi, unsigned lo) {
  return __longlong_as_double(((long long)hi << 32) | lo);
}
template <int CTRL, int RM>
__device__ __forceinline__ double kstep_d(double k) {
  long long bb = __double_as_longlong(k);
  unsigned lo = (unsigned)bb, hi = (unsigned)(bb >> 32);
  unsigned olo = (unsigned)dppi<CTRL, RM>((int)lo);
  unsigned ohi = (unsigned)dppi<CTRL, RM>((int)hi);
  double o = __longlong_as_double(((long long)ohi << 32) | olo);
  return fmax(k, o);
}
__device__ __forceinline__ double wave_max_key_d(double key) {
  key = kstep_d<0x111, 0xf>(key);  // row_shr:1
  key = kstep_d<0x112, 0xf>(key);  // row_shr:2
  key = kstep_d<0x114, 0xf>(key);  // row_shr:4
  key = kstep_d<0x118, 0xf>(key);  // row_shr:8
  key = kstep_d<0x142, 0xa>(key);  // row_bcast:15
  key = kstep_d<0x143, 0xc>(key);  // row_bcast:31
  return key;
}
// wave-64 inclusive add-scan (valid all lanes; lane63 = total)
__device__ __forceinline__ unsigned wave_scan_incl(unsigned v) {
  v += (unsigned)__builtin_amdgcn_update_dpp(0, (int)v, 0x111, 0xf, 0xf, true);
  v += (unsigned)__builtin_amdgcn_update_dpp(0, (int)v, 0x112, 0xf, 0xf, true);
  v += (unsigned)__builtin_amdgcn_update_dpp(0, (int)v, 0x114, 0xf, 0xf, true);
  v += (unsigned)__builtin_amdgcn_update_dpp(0, (int)v, 0x118, 0xf, 0xf, true);
  v += (unsigned)__builtin_amdgcn_update_dpp(0, (int)v, 0x142, 0xa, 0xf, true);
  v += (unsigned)__builtin_amdgcn_update_dpp(0, (int)v, 0x143, 0xc, 0xf, true);
  return v;
}

__device__ __forceinline__ int cell16(float x) {
  int c = (int)(x * 16.0f);
  return c > 15 ? 15 : (c < 0 ? 0 : c);
}
__device__ __forceinline__ unsigned morton12(int ix, int iy, int iz) {
  unsigned m = 0;
#pragma unroll
  for (int k = 0; k < 4; ++k) {
    m |= ((unsigned)((ix >> k) & 1) << (3 * k + 2)) |
         ((unsigned)((iy >> k) & 1) << (3 * k + 1)) |
         ((unsigned)((iz >> k) & 1) << (3 * k + 0));
  }
  return m;
}

// ---------------- FPS: one block per batch, 512 threads, lane prune ---------
__global__ __launch_bounds__(512) void fps_kernel(const float* __restrict__ xyz,
                                                  float* __restrict__ new_xyz) {
  const int b = blockIdx.x;
  const int tid = threadIdx.x;
  const int lane = tid & 63;
  const int wid = tid >> 6;
  __shared__ float sx[NPTS], sy[NPTS], sz[NPTS];   // original order
  __shared__ unsigned short sidx16[NPTS];          // sorted pos -> orig idx
  __shared__ unsigned offs[4096];
  __shared__ unsigned wsum[8];
  __shared__ int farhist[NPOINT];
  __shared__ __align__(16) double skey[2][8];

  const float* xb = xyz + (size_t)b * NPTS * 3;
  for (int i = tid; i < NPTS; i += 512) {
    sx[i] = xb[3 * i + 0];
    sy[i] = xb[3 * i + 1];
    sz[i] = xb[3 * i + 2];
  }
  for (int i = tid; i < 4096; i += 512) offs[i] = 0;
  __syncthreads();
  for (int r = 0; r < 16; ++r) {
    int i = tid + r * 512;
    atomicAdd(&offs[morton12(cell16(sx[i]), cell16(sy[i]), cell16(sz[i]))], 1u);
  }
  __syncthreads();
  unsigned loc[8];
  unsigned s = 0;
#pragma unroll
  for (int q = 0; q < 8; ++q) {
    loc[q] = s;
    s += offs[tid * 8 + q];
  }
  unsigned inc = wave_scan_incl(s);
  if (lane == 63) wsum[wid] = inc;
  __syncthreads();
  unsigned pre = 0;
#pragma unroll
  for (int w = 0; w < 8; ++w) pre += (w < wid) ? wsum[w] : 0u;
  unsigned excl = pre + inc - s;
  __syncthreads();
#pragma unroll
  for (int q = 0; q < 8; ++q) offs[tid * 8 + q] = excl + loc[q];
  __syncthreads();
  for (int r = 0; r < 16; ++r) {
    int i = tid + r * 512;
    unsigned m = morton12(cell16(sx[i]), cell16(sy[i]), cell16(sz[i]));
    unsigned pos = atomicAdd(&offs[m], 1u);
    sidx16[pos] = (unsigned short)i;
  }
  __syncthreads();

  f32x2 px[8], py[8], pz[8];
  float dist[16];
  unsigned noid[16];  // ~origidx
  float blx = 1e30f, bhx = -1e30f, bly = 1e30f, bhy = -1e30f,
        blz = 1e30f, bhz = -1e30f;
#pragma unroll
  for (int j = 0; j < 8; ++j) {
    unsigned i0 = sidx16[tid * 16 + 2 * j], i1 = sidx16[tid * 16 + 2 * j + 1];
    noid[2 * j] = ~i0; noid[2 * j + 1] = ~i1;
    float x0 = sx[i0], x1 = sx[i1];
    float y0 = sy[i0], y1 = sy[i1];
    float z0 = sz[i0], z1 = sz[i1];
    px[j].x = x0; px[j].y = x1;
    py[j].x = y0; py[j].y = y1;
    pz[j].x = z0; pz[j].y = z1;
    blx = fminf(blx, fminf(x0, x1)); bhx = fmaxf(bhx, fmaxf(x0, x1));
    bly = fminf(bly, fminf(y0, y1)); bhy = fmaxf(bhy, fmaxf(y0, y1));
    blz = fminf(blz, fminf(z0, z1)); bhz = fmaxf(bhz, fmaxf(z0, z1));
    dist[2 * j] = 1e10f; dist[2 * j + 1] = 1e10f;
  }
  float gmaxd = 1e30f;  // forces update on iter 0
  double gkey = 0.0;
  int far = 0;
  for (int it = 0; it < NPOINT; ++it) {
    if (tid == 0) farhist[it] = far;
    const float cx = sx[far], cy = sy[far], cz = sz[far];
    float gx = fmaxf(fmaxf(blx - cx, cx - bhx), 0.f);
    float gy = fmaxf(fmaxf(bly - cy, cy - bhy), 0.f);
    float gz = fmaxf(fmaxf(blz - cz, cz - bhz), 0.f);
    float mind2 = gx * gx + gy * gy + gz * gz;
    if (mind2 * 0.999f < gmaxd) {
      f32x2 ncx, ncy, ncz;
      ncx.x = -cx; ncx.y = -cx;
      ncy.x = -cy; ncy.y = -cy;
      ncz.x = -cz; ncz.y = -cz;
      double kk[16];
#pragma unroll
      for (int j = 0; j < 8; ++j) {
        // exact numpy rounding: (dx^2 + dy^2) + dz^2, RN each step, no FMA
        f32x2 dx = pk_add(px[j], ncx);
        f32x2 dy = pk_add(py[j], ncy);
        f32x2 dz = pk_add(pz[j], ncz);
        f32x2 xx = pk_mul(dx, dx);
        f32x2 yy = pk_mul(dy, dy);
        f32x2 dd = pk_add(pk_add(xx, yy), pk_mul(dz, dz));
        float n0 = fminf(dist[2 * j], dd.x);
        float n1 = fminf(dist[2 * j + 1], dd.y);
        dist[2 * j] = n0; dist[2 * j + 1] = n1;
        kk[2 * j] = mkkey(__float_as_uint(n0), noid[2 * j]);
        kk[2 * j + 1] = mkkey(__float_as_uint(n1), noid[2 * j + 1]);
      }
      // depth-4 max tree (fmax associative for our non-NaN keys); chain of 16
      // dependent v_max_f64 would sit on the straggler wave's critical path.
#pragma unroll
      for (int st = 1; st < 16; st <<= 1)
#pragma unroll
        for (int j = 0; j < 16; j += 2 * st) kk[j] = kmax(kk[j], kk[j + st]);
      gkey = kk[0];
      gmaxd = __uint_as_float((unsigned)((u64)__double_as_longlong(kk[0]) >> 32));
    }
    double key = wave_max_key_d(gkey);
    const int p = it & 1;
    if (lane == 63) skey[p][wid] = key;
    __syncthreads();
    const double2* kp = (const double2*)&skey[p][0];
    double2 a0 = kp[0], a1 = kp[1], a2 = kp[2], a3 = kp[3];
    double q0 = kmax(a0.x, a0.y), q1 = kmax(a1.x, a1.y);
    double q2 = kmax(a2.x, a2.y), q3 = kmax(a3.x, a3.y);
    double best = kmax(kmax(q0, q1), kmax(q2, q3));
    far = (int)~(unsigned)(u64)__double_as_longlong(best);
  }
  __syncthreads();
  for (int t = tid; t < NPOINT; t += 512) {
    int f = farhist[t];
    float* o = new_xyz + ((size_t)b * NPOINT + t) * 3;
    o[0] = sx[f]; o[1] = sy[f]; o[2] = sz[f];
  }
}

// ---------------- feature transpose (B,C,N) -> (B,N,C) ----------------
__global__ __launch_bounds__(256) void tr_kernel(const float* __restrict__ f,
                                                 float* __restrict__ ft) {
  int idx = blockIdx.x * 256 + threadIdx.x;
  int c = idx & 63;
  int i = (idx >> 6) & (NPTS - 1);
  int b = idx >> 19;
  ft[idx] = f[((size_t)(b * CF + c)) * NPTS + i];
}

// ---------------- ball query: one wave per center ----------------
__global__ __launch_bounds__(256) void bq_kernel(const float* __restrict__ xyz,
                                                 const float* __restrict__ new_xyz,
                                                 int* __restrict__ idxbuf) {
  const int lane = threadIdx.x & 63;
  const int gw = (blockIdx.x * 256 + threadIdx.x) >> 6;
  const int b = gw >> 11;
  const int j = gw & 2047;
  const float* xb = xyz + (size_t)b * NPTS * 3;
  const float* c = new_xyz + ((size_t)b * NPOINT + j) * 3;
  const float cx = c[0], cy = c[1], cz = c[2];
  int* out = idxbuf + ((size_t)b * NPOINT + j) * NSAMPLE;
  const float r2 = 0.01f;
  int found = 0, first = 0;
  for (int base = 0; base < NPTS && found < NSAMPLE; base += 64) {
    const int i = base + lane;
    float dx = xb[3 * i + 0] - cx, dy = xb[3 * i + 1] - cy, dz = xb[3 * i + 2] - cz;
    float d = __fadd_rn(__fadd_rn(__fmul_rn(dx, dx), __fmul_rn(dy, dy)),
                        __fmul_rn(dz, dz));
    bool in = (d <= r2);
    unsigned long long mask = __ballot(in);
    if (mask) {
      if (found == 0) first = base + (__ffsll(mask) - 1);
      int slot = found + __popcll(mask & ((1ull << lane) - 1ull));
      if (in && slot < NSAMPLE) out[slot] = i;
      found += (int)__popcll(mask);
    }
  }
  for (int s = found + lane; s < NSAMPLE; s += 64) out[s] = first;
}

// ---------------- fused gather + MLP + max ----------------
__global__ __launch_bounds__(256) void mlp_kernel(const float* __restrict__ xyz,
                                                  const float* __restrict__ ft,
                                                  const float* __restrict__ feat,
                                                  const int* __restrict__ idxbuf,
                                                  const float* __restrict__ new_xyz,
                                                  const float* __restrict__ W0,
                                                  const float* __restrict__ b0,
                                                  const float* __restrict__ W1,
                                                  const float* __restrict__ b1,
                                                  const float* __restrict__ W2,
                                                  const float* __restrict__ b2,
                                                  float* __restrict__ out_nf,
                                                  int use_ft) {
  __shared__ __align__(16) float Ws0[CIN * 64];   // [c][o]
  __shared__ __align__(16) float Ws1[64 * 64];    // [c][o]
  __shared__ __align__(16) float Ws2[64 * 128];   // [c][o]
  __shared__ float bs0[64], bs1[64], bs2[128];
  __shared__ __align__(16) float X0[CIN * 32];    // [c][k]
  __shared__ __align__(16) float X1[64 * 32];     // [c][k]
  const int tid = threadIdx.x;
  const int k = tid & 31;
  const int og = tid >> 5;  // 0..7
  for (int t = tid; t < 64 * CIN; t += 256) {
    int o = t / CIN, c = t - o * CIN;
    Ws0[c * 64 + o] = W0[t];
  }
  for (int t = tid; t < 64 * 64; t += 256) Ws1[(t & 63) * 64 + (t >> 6)] = W1[t];
  for (int t = tid; t < 128 * 64; t += 256) Ws2[(t & 63) * 128 + (t >> 6)] = W2[t];
  if (tid < 64) { bs0[tid] = b0[tid]; bs1[tid] = b1[tid]; }
  if (tid < 128) bs2[tid] = b2[tid];
  __syncthreads();

  for (int g = 0; g < G; ++g) {
    const int cj = blockIdx.x * G + g;
    const int b = cj >> 11;
    const int j = cj & 2047;
    const int ni = idxbuf[cj * NSAMPLE + k];
    if (og == 0) {
      const float* ctr = new_xyz + (size_t)cj * 3;
      const float* pp = xyz + ((size_t)b * NPTS + ni) * 3;
      X0[0 * 32 + k] = pp[0] - ctr[0];
      X0[1 * 32 + k] = pp[1] - ctr[1];
      X0[2 * 32 + k] = pp[2] - ctr[2];
    }
    const int cbase = 3 + og * 8;
    if (use_ft) {
      const float4* fr = (const float4*)(ft + ((size_t)b * NPTS + ni) * CF + og * 8);
      float4 f0 = fr[0], f1 = fr[1];
      X0[(cbase + 0) * 32 + k] = f0.x; X0[(cbase + 1) * 32 + k] = f0.y;
      X0[(cbase + 2) * 32 + k] = f0.z; X0[(cbase + 3) * 32 + k] = f0.w;
      X0[(cbase + 4) * 32 + k] = f1.x; X0[(cbase + 5) * 32 + k] = f1.y;
      X0[(cbase + 6) * 32 + k] = f1.z; X0[(cbase + 7) * 32 + k] = f1.w;
    } else {
      const float* fb = feat + (size_t)b * CF * NPTS + ni;
#pragma unroll
      for (int q = 0; q < 8; ++q)
        X0[(cbase + q) * 32 + k] = fb[(size_t)(og * 8 + q) * NPTS];
    }
    __syncthreads();

    // L0: 67 -> 64
    float acc[8];
#pragma unroll
    for (int i = 0; i < 8; ++i) acc[i] = bs0[og * 8 + i];
    for (int c = 0; c < CIN; ++c) {
      float xv = X0[c * 32 + k];
      const float4* wr = (const float4*)&Ws0[c * 64 + og * 8];
      float4 w0 = wr[0], w1 = wr[1];
      acc[0] = fmaf(w0.x, xv, acc[0]); acc[1] = fmaf(w0.y, xv, acc[1]);
      acc[2] = fmaf(w0.z, xv, acc[2]); acc[3] = fmaf(w0.w, xv, acc[3]);
      acc[4] = fmaf(w1.x, xv, acc[4]); acc[5] = fmaf(w1.y, xv, acc[5]);
      acc[6] = fmaf(w1.z, xv, acc[6]); acc[7] = fmaf(w1.w, xv, acc[7]);
    }
#pragma unroll
    for (int i = 0; i < 8; ++i) X1[(og * 8 + i) * 32 + k] = fmaxf(acc[i], 0.f);
    __syncthreads();

    // L1: 64 -> 64 (reads X1, writes X0)
    float a1[8];
#pragma unroll
    for (int i = 0; i < 8; ++i) a1[i] = bs1[og * 8 + i];
    for (int c = 0; c < 64; ++c) {
      float xv = X1[c * 32 + k];
      const float4* wr = (const float4*)&Ws1[c * 64 + og * 8];
      float4 w0 = wr[0], w1 = wr[1];
      a1[0] = fmaf(w0.x, xv, a1[0]); a1[1] = fmaf(w0.y, xv, a1[1]);
      a1[2] = fmaf(w0.z, xv, a1[2]); a1[3] = fmaf(w0.w, xv, a1[3]);
      a1[4] = fmaf(w1.x, xv, a1[4]); a1[5] = fmaf(w1.y, xv, a1[5]);
      a1[6] = fmaf(w1.z, xv, a1[6]); a1[7] = fmaf(w1.w, xv, a1[7]);
    }
#pragma unroll
    for (int i = 0; i < 8; ++i) X0[(og * 8 + i) * 32 + k] = fmaxf(a1[i], 0.f);
    __syncthreads();

    // L2: 64 -> 128 (reads X0 rows 0..63), fused relu + max over k
    float a2[16];
#pragma unroll
    for (int i = 0; i < 16; ++i) a2[i] = bs2[og * 16 + i];
    for (int c = 0; c < 64; ++c) {
      float xv = X0[c * 32 + k];
      const float4* wr = (const float4*)&Ws2[c * 128 + og * 16];
      float4 w0 = wr[0], w1 = wr[1], w2 = wr[2], w3 = wr[3];
      a2[0]  = fmaf(w0.x, xv, a2[0]);  a2[1]  = fmaf(w0.y, xv, a2[1]);
      a2[2]  = fmaf(w0.z, xv, a2[2]);  a2[3]  = fmaf(w0.w, xv, a2[3]);
      a2[4]  = fmaf(w1.x, xv, a2[4]);  a2[5]  = fmaf(w1.y, xv, a2[5]);
      a2[6]  = fmaf(w1.z, xv, a2[6]);  a2[7]  = fmaf(w1.w, xv, a2[7]);
      a2[8]  = fmaf(w2.x, xv, a2[8]);  a2[9]  = fmaf(w2.y, xv, a2[9]);
      a2[10] = fmaf(w2.z, xv, a2[10]); a2[11] = fmaf(w2.w, xv, a2[11]);
      a2[12] = fmaf(w3.x, xv, a2[12]); a2[13] = fmaf(w3.y, xv, a2[13]);
      a2[14] = fmaf(w3.z, xv, a2[14]); a2[15] = fmaf(w3.w, xv, a2[15]);
    }
#pragma unroll
    for (int i = 0; i < 16; ++i) {
      float v = fmaxf(a2[i], 0.f);
#pragma unroll
      for (int m = 1; m < 32; m <<= 1) v = fmaxf(v, __shfl_xor(v, m));
      a2[i] = v;
    }
    if (k == 0) {
#pragma unroll
      for (int i = 0; i < 16; ++i)
        out_nf[((size_t)b * 128 + og * 16 + i) * NPOINT + j] = a2[i];
    }
    __syncthreads();
  }
}

extern "C" void kernel_launch(void* const* d_in, const int* in_sizes, int n_in,
                              void* d_out, int out_size, void* d_ws, size_t ws_size,
                              hipStream_t stream) {
  (void)in_sizes; (void)n_in; (void)out_size;
  const float* xyz  = (const float*)d_in[0];
  const float* feat = (const float*)d_in[1];
  const float* W0   = (const float*)d_in[2];
  const float* b0   = (const float*)d_in[3];
  const float* W1   = (const float*)d_in[4];
  const float* b1   = (const float*)d_in[5];
  const float* W2   = (const float*)d_in[6];
  const float* b2   = (const float*)d_in[7];
  float* new_xyz = (float*)d_out;
  float* out_nf  = (float*)d_out + (size_t)NB * NPOINT * 3;

  int* idxbuf = (int*)d_ws;
  size_t idx_bytes = (size_t)NB * NPOINT * NSAMPLE * sizeof(int);
  float* ft = (float*)((char*)d_ws + idx_bytes);
  size_t need = idx_bytes + (size_t)NB * NPTS * CF * sizeof(float);
  int use_ft = (ws_size >= need) ? 1 : 0;

  fps_kernel<<<NB, 512, 0, stream>>>(xyz, new_xyz);
  if (use_ft) tr_kernel<<<(NB * NPTS * CF) / 256, 256, 0, stream>>>(feat, ft);
  bq_kernel<<<(NB * NPOINT) / 4, 256, 0, stream>>>(xyz, new_xyz, idxbuf);
  mlp_kernel<<<(NB * NPOINT) / G, 256, 0, stream>>>(xyz, ft, feat, idxbuf, new_xyz,
                                                    W0, b0, W1, b1, W2, b2,
                                                    out_nf, use_ft);
}